// Round 4
// baseline (668.705 us; speedup 1.0000x reference)
//
#include <hip/hip_runtime.h>
#include <hip/hip_bf16.h>

typedef __attribute__((ext_vector_type(8))) short short8;   // 8 bf16 (4 VGPRs)
typedef __attribute__((ext_vector_type(4))) float f32x4;    // MFMA 16x16 acc

static __device__ __forceinline__ short f2b(float f) {
    union { float f; unsigned u; } v; v.f = f;
    unsigned r = v.u + 0x7FFFu + ((v.u >> 16) & 1u);   // RNE
    return (short)(r >> 16);
}
static __device__ __forceinline__ float b2f(short s) {
    union { unsigned u; float f; } v;
    v.u = ((unsigned)(unsigned short)s) << 16;
    return v.f;
}
static __device__ __forceinline__ unsigned char f2fp8(float f) {
    return (unsigned char)(__builtin_amdgcn_cvt_pk_fp8_f32(f, f, 0, false) & 0xff);
}

// ---------------------------------------------------------------------------
// prep_w: AWT[448][416] bf16 (AWT[m][n]=A[n][m]*W1[n][m], zero-pad),
//         W2Tb[400][64] bf16, W3Tb[64][64] bf16,
//         AbT[400][448] bytes (AbT[j][m] = A[m][j]!=0).
// grid: 1544 x 256 = 395264 = 186368 + 25600 + 4096 + 179200
// ---------------------------------------------------------------------------
__global__ __launch_bounds__(256) void prep_w(
    const float* __restrict__ A, const float* __restrict__ W1,
    const float* __restrict__ W2, const float* __restrict__ W3,
    short* __restrict__ AWT, short* __restrict__ W2Tb,
    short* __restrict__ W3Tb, unsigned char* __restrict__ AbT)
{
    int i = blockIdx.x * 256 + threadIdx.x;
    if (i < 186368) {
        int m = i / 416, n = i - m * 416;
        AWT[i] = (m < 400 && n < 400) ? f2b(A[n * 400 + m] * W1[n * 400 + m])
                                      : (short)0;
    } else if (i < 211968) {
        int i2 = i - 186368;
        int j = i2 >> 6, f = i2 & 63;
        W2Tb[i2] = f2b(W2[f * 400 + j]);
    } else if (i < 216064) {
        int i3 = i - 211968;
        int u = i3 >> 6, f = i3 & 63;
        W3Tb[i3] = f2b(W3[f * 64 + u]);
    } else {
        int i4 = i - 216064;
        int j = i4 / 448, m = i4 - j * 448;
        AbT[i4] = (m < 400 && A[m * 400 + j] != 0.f) ? 1 : 0;
    }
}

// ---------------------------------------------------------------------------
// prep_xt: xTb[bt][f][n s416] bf16 and xT8[bt][f][n s416] fp8 from x.
// ---------------------------------------------------------------------------
__global__ __launch_bounds__(256) void prep_xt(
    const float* __restrict__ x, short* __restrict__ xTb,
    unsigned char* __restrict__ xT8)
{
    int bt = blockIdx.x, tid = threadIdx.x;
    __shared__ float tile[64][65];
    const float* xs = x + (size_t)bt * 25600;
    short* xo = xTb + (size_t)bt * 64 * 416;
    unsigned char* x8 = xT8 + (size_t)bt * 64 * 416;
    for (int c = 0; c < 7; ++c) {
        int n0 = c * 64, cnt = (c == 6) ? 16 : 64;
        __syncthreads();
        for (int i = tid; i < cnt * 64; i += 256) {
            int r = i >> 6, f = i & 63;
            tile[r][f] = xs[(size_t)(n0 + r) * 64 + f];
        }
        __syncthreads();
        for (int i = tid; i < cnt * 64; i += 256) {
            int r = i & (cnt - 1), f = i / cnt;
            float v = tile[r][f];
            xo[(size_t)f * 416 + n0 + r] = f2b(v);
            x8[(size_t)f * 416 + n0 + r] = f2fp8(v);
        }
    }
    for (int i = tid; i < 64 * 16; i += 256) {
        int f = i >> 4, n = 400 + (i & 15);
        xo[(size_t)f * 416 + n] = 0;
        x8[(size_t)f * 416 + n] = 0;
    }
}

// ---------------------------------------------------------------------------
// dgc_mfma v2: barrier-free, all LDS wave-private, attn in fp8.
// grid (480 bt, 7 m-tiles), 4 waves; wave w owns rows [mt*64+w*16, +16).
// LDS: attnS8 64x432 fp8 (27648 B) + featS 64x72 bf16 (9216 B) = 36864 B
//   -> 4 blocks/CU at <=128 VGPR (launch_bounds(256,4)).
// Softmax: no max-pass (logits are small: weights ~0.05 scale), mask via
// AbT byte-matrix (1 dword = 4 rows' masks).
// ---------------------------------------------------------------------------
__global__ __launch_bounds__(256, 4) void dgc_mfma(
    const float* __restrict__ b1p, const float* __restrict__ b2p,
    const unsigned* __restrict__ AbT32,
    const short* __restrict__ AWT, const short* __restrict__ W2Tb,
    const short* __restrict__ W3Tb, const short* __restrict__ xTb,
    const unsigned char* __restrict__ xT8,
    short* __restrict__ y)
{
    int bt = blockIdx.x, mt = blockIdx.y;
    int tid = threadIdx.x, lane = tid & 63, w = tid >> 6;
    int lm = lane & 15, quad = lane >> 4;

    __shared__ __align__(16) char  attnS8[64 * 432];
    __shared__ __align__(16) short featS[64 * 72];

    // zero own strip's pad cols [400,432) — wave-private, no barrier
    *(long*)&attnS8[(w * 16 + lm) * 432 + 400 + quad * 8] = 0;

    const short* xt = xTb + (size_t)bt * 64 * 416;
    const unsigned char* xt8 = xT8 + (size_t)bt * 64 * 416;

    // ---- Phase A: feat stripe [16 x 64] = AWT @ x (bf16) ----
    f32x4 fa[4];
#pragma unroll
    for (int i = 0; i < 4; ++i) fa[i] = (f32x4){0.f, 0.f, 0.f, 0.f};
    const short* awt_row = AWT + (size_t)(mt * 64 + w * 16 + lm) * 416 + quad * 8;
#pragma unroll
    for (int k0 = 0; k0 < 416; k0 += 32) {
        short8 af = *(const short8*)(awt_row + k0);
#pragma unroll
        for (int ft = 0; ft < 4; ++ft) {
            short8 bf = *(const short8*)(xt + (size_t)(ft * 16 + lm) * 416 + k0 + quad * 8);
            fa[ft] = __builtin_amdgcn_mfma_f32_16x16x32_bf16(af, bf, fa[ft], 0, 0, 0);
        }
    }
#pragma unroll
    for (int ft = 0; ft < 4; ++ft)
#pragma unroll
        for (int r = 0; r < 4; ++r)
            featS[(w * 16 + quad * 4 + r) * 72 + ft * 16 + lm] = f2b(fa[ft][r]);

    // ---- Phase B: dense stripe [16 x 400] = feat @ W2, mask, softmax ----
    f32x4 da[25];
#pragma unroll
    for (int jt = 0; jt < 25; ++jt) da[jt] = (f32x4){0.f, 0.f, 0.f, 0.f};
    short8 a0 = *(const short8*)&featS[(w * 16 + lm) * 72 + quad * 8];
    short8 a1 = *(const short8*)&featS[(w * 16 + lm) * 72 + 32 + quad * 8];
#pragma unroll
    for (int jt = 0; jt < 25; ++jt) {
        short8 bf0 = *(const short8*)(W2Tb + (size_t)(jt * 16 + lm) * 64 + quad * 8);
        short8 bf1 = *(const short8*)(W2Tb + (size_t)(jt * 16 + lm) * 64 + 32 + quad * 8);
        da[jt] = __builtin_amdgcn_mfma_f32_16x16x32_bf16(a0, bf0, da[jt], 0, 0, 0);
        da[jt] = __builtin_amdgcn_mfma_f32_16x16x32_bf16(a1, bf1, da[jt], 0, 0, 0);
    }
    int mrb = mt * 64 + w * 16 + quad * 4;          // 4-aligned
#pragma unroll
    for (int jt = 0; jt < 25; ++jt) {
        float b1v = b1p[jt * 16 + lm];
        unsigned mv = AbT32[(size_t)(jt * 16 + lm) * 112 + (mrb >> 2)];
#pragma unroll
        for (int r = 0; r < 4; ++r) {
            float e = ((mv >> (8 * r)) & 255u) ? __expf(da[jt][r] + b1v) : 0.f;
            da[jt][r] = e;
        }
    }
    float inv_s[4];
#pragma unroll
    for (int r = 0; r < 4; ++r) {
        float s = 0.f;
#pragma unroll
        for (int jt = 0; jt < 25; ++jt) s += da[jt][r];
        s += __shfl_xor(s, 1);
        s += __shfl_xor(s, 2);
        s += __shfl_xor(s, 4);
        s += __shfl_xor(s, 8);
        inv_s[r] = 1.f / s;
    }
#pragma unroll
    for (int jt = 0; jt < 25; ++jt)
#pragma unroll
        for (int r = 0; r < 4; ++r)
            attnS8[(w * 16 + quad * 4 + r) * 432 + jt * 16 + lm] =
                (char)f2fp8(da[jt][r] * inv_s[r]);

    // ---- Phase D: nodef stripe [16 x 64] = attn @ x (fp8 MFMA) ----
    f32x4 na[4];
#pragma unroll
    for (int i = 0; i < 4; ++i) na[i] = (f32x4){0.f, 0.f, 0.f, 0.f};
    const char* at_row = attnS8 + (w * 16 + lm) * 432 + quad * 8;
#pragma unroll
    for (int k0 = 0; k0 < 416; k0 += 32) {
        long af8 = *(const long*)(at_row + k0);
#pragma unroll
        for (int ft = 0; ft < 4; ++ft) {
            long bf8 = *(const long*)(xt8 + (size_t)(ft * 16 + lm) * 416 + k0 + quad * 8);
            na[ft] = __builtin_amdgcn_mfma_f32_16x16x32_fp8_fp8(af8, bf8, na[ft], 0, 0, 0);
        }
    }
    // reuse featS (wave-private strip) for nodef
#pragma unroll
    for (int ft = 0; ft < 4; ++ft)
#pragma unroll
        for (int r = 0; r < 4; ++r)
            featS[(w * 16 + quad * 4 + r) * 72 + ft * 16 + lm] = f2b(na[ft][r]);

    // ---- Phase E: y stripe [16 x 64] = nodef @ W3 + b2 (bf16 out) ----
    f32x4 ya[4];
#pragma unroll
    for (int i = 0; i < 4; ++i) ya[i] = (f32x4){0.f, 0.f, 0.f, 0.f};
    short8 n0 = *(const short8*)&featS[(w * 16 + lm) * 72 + quad * 8];
    short8 n1 = *(const short8*)&featS[(w * 16 + lm) * 72 + 32 + quad * 8];
#pragma unroll
    for (int ut = 0; ut < 4; ++ut) {
        short8 bf0 = *(const short8*)(W3Tb + (size_t)(ut * 16 + lm) * 64 + quad * 8);
        short8 bf1 = *(const short8*)(W3Tb + (size_t)(ut * 16 + lm) * 64 + 32 + quad * 8);
        ya[ut] = __builtin_amdgcn_mfma_f32_16x16x32_bf16(n0, bf0, ya[ut], 0, 0, 0);
        ya[ut] = __builtin_amdgcn_mfma_f32_16x16x32_bf16(n1, bf1, ya[ut], 0, 0, 0);
    }
#pragma unroll
    for (int ut = 0; ut < 4; ++ut) {
        int u = ut * 16 + lm;
        float b2v = b2p[u];
#pragma unroll
        for (int r = 0; r < 4; ++r) {
            int mrow = mrb + r;
            if (mrow < 400)
                y[((size_t)bt * 400 + mrow) * 64 + u] = f2b(ya[ut][r] + b2v);
        }
    }
}

// ---------------------------------------------------------------------------
// ta_r1_rhs (y now bf16): r1[bt,f]=sum_n y*taW1[n]; rhs[bt,n]=sum_f y*taW3[f]
// ---------------------------------------------------------------------------
__global__ __launch_bounds__(256) void ta_r1_rhs(
    const short* __restrict__ y, const float* __restrict__ taW1,
    const float* __restrict__ taW3, float* __restrict__ r1,
    float* __restrict__ rhs)
{
    int bt = blockIdx.x;
    const short* ys = y + (size_t)bt * 25600;
    int tid = threadIdx.x, lane = tid & 63, w = tid >> 6;
    __shared__ __align__(16) float part[4][64];
    __shared__ __align__(16) float w3s[64];
    if (tid < 64) w3s[tid] = taW3[tid];
    float acc = 0.f;
    for (int n = w * 100; n < w * 100 + 100; ++n)
        acc += taW1[n] * b2f(ys[(size_t)n * 64 + lane]);
    part[w][lane] = acc;
    __syncthreads();
    if (w == 0)
        r1[bt * 64 + lane] = part[0][lane] + part[1][lane] + part[2][lane] + part[3][lane];
    for (int n = tid; n < 400; n += 256) {
        const short8* yr = (const short8*)(ys + (size_t)n * 64);
        float a = 0.f;
#pragma unroll
        for (int q = 0; q < 8; ++q) {
            short8 v = yr[q];
#pragma unroll
            for (int e = 0; e < 8; ++e) a += b2f(v[e]) * w3s[q * 8 + e];
        }
        rhs[bt * 400 + n] = a;
    }
}

// ---------------------------------------------------------------------------
// ta_lhs: lhs[bt,n] = sum_f r1[bt,f] * taW2[f,n]
// ---------------------------------------------------------------------------
__global__ __launch_bounds__(256) void ta_lhs(
    const float* __restrict__ r1, const float* __restrict__ taW2,
    float* __restrict__ lhs)
{
    int bt = blockIdx.x, tid = threadIdx.x;
    __shared__ float r1s[64];
    if (tid < 64) r1s[tid] = r1[bt * 64 + tid];
    __syncthreads();
    for (int n = tid; n < 400; n += 256) {
        float acc = 0.f;
#pragma unroll 8
        for (int f = 0; f < 64; ++f) acc += r1s[f] * taW2[f * 400 + n];
        lhs[bt * 400 + n] = acc;
    }
}

// ---------------------------------------------------------------------------
// ta_product: S[b,k,l] = sigmoid( lhs[b,k,:].rhs[b,l,:] + be[k,l] )
// ---------------------------------------------------------------------------
__global__ __launch_bounds__(256) void ta_product(
    const float* __restrict__ lhs, const float* __restrict__ rhs,
    const float* __restrict__ be, float* __restrict__ S)
{
    int kc = blockIdx.x, b = blockIdx.y, tid = threadIdx.x;
    if (tid >= 240) return;
    int k = kc * 4 + tid / 60;
    int l = tid % 60;
    const float4* lr = (const float4*)(lhs + (size_t)(b * 60 + k) * 400);
    const float4* rr = (const float4*)(rhs + (size_t)(b * 60 + l) * 400);
    float acc = 0.f;
    for (int q = 0; q < 100; ++q) {
        float4 a = lr[q], c = rr[q];
        acc += a.x * c.x + a.y * c.y + a.z * c.z + a.w * c.w;
    }
    float v = acc + be[k * 60 + l];
    S[b * 3600 + k * 60 + l] = 1.f / (1.f + __expf(-v));
}

// ---------------------------------------------------------------------------
// ta_softmax: E[b,j,l] = sum_k Ve[j,k]*S[b,k,l]; ker = softmax over j.
// ---------------------------------------------------------------------------
__global__ __launch_bounds__(256) void ta_softmax(
    const float* __restrict__ S, const float* __restrict__ Ve,
    float* __restrict__ ker)
{
    int b = blockIdx.x, tid = threadIdx.x;
    __shared__ float Ss[3600];
    __shared__ float Emat[3600];
    for (int i = tid; i < 3600; i += 256) Ss[i] = S[b * 3600 + i];
    __syncthreads();
    for (int p = tid; p < 3600; p += 256) {
        int j = p / 60, l = p % 60;
        float acc = 0.f;
        for (int k = 0; k < 60; ++k) acc += Ve[j * 60 + k] * Ss[k * 60 + l];
        Emat[p] = acc;
    }
    __syncthreads();
    for (int l = tid; l < 60; l += 256) {
        float mx = -1e30f;
        for (int j = 0; j < 60; ++j) mx = fmaxf(mx, Emat[j * 60 + l]);
        float s = 0.f;
        for (int j = 0; j < 60; ++j) s += __expf(Emat[j * 60 + l] - mx);
        float inv = 1.f / s;
        for (int j = 0; j < 60; ++j)
            ker[b * 3600 + j * 60 + l] = __expf(Emat[j * 60 + l] - mx) * inv;
    }
}

// ---------------------------------------------------------------------------
// kt_prep: KT[u][dt*128+c] = bf16( c<64 ? tk[dt,0,c,u] : rk[dt,0,c-64,u] )
// ---------------------------------------------------------------------------
__global__ __launch_bounds__(256) void kt_prep(
    const float* __restrict__ tk, const float* __restrict__ rk,
    short* __restrict__ KT)
{
    int i = blockIdx.x * 256 + threadIdx.x;      // [0, 98304)
    int u = i / 1536, kk = i - u * 1536;
    int dt = kk >> 7, c = kk & 127;
    float v = (c < 64) ? tk[dt * 4096 + c * 64 + u]
                       : rk[dt * 4096 + (c - 64) * 64 + u];
    KT[i] = f2b(v);
}

// ---------------------------------------------------------------------------
// fused_conv: time-mix + both temporal convs + softplus, bf16 MFMA.
// y input now bf16 (no conversion on staging).
// ---------------------------------------------------------------------------
__global__ __launch_bounds__(256, 4) void fused_conv(
    const short* __restrict__ y, const float* __restrict__ ker,
    const float* __restrict__ x, const short* __restrict__ KT,
    const float* __restrict__ tb, const float* __restrict__ rb,
    float* __restrict__ out)
{
    int n = blockIdx.x, b = blockIdx.y;
    int tid = threadIdx.x, lane = tid & 63, w = tid >> 6;
    int m = lane & 15, quad = lane >> 4;
    int hm = w >> 1, hn = w & 1;

    __shared__ __align__(16) short In[75 * 136];
    __shared__ __align__(16) short kerT[64 * 72];
    __shared__ __align__(16) short ybT[64 * 72];

    for (int i = tid; i < 75 * 136; i += 256) In[i] = 0;
    for (int i = tid; i < 64 * 72; i += 256) { kerT[i] = 0; ybT[i] = 0; }
    __syncthreads();

    for (int i = tid; i < 3840; i += 256) {
        int t = i >> 6, u = i & 63;
        In[(t + 5) * 136 + 64 + u] = f2b(x[((size_t)(b * 60 + t) * 400 + n) * 64 + u]);
    }
    for (int i = tid; i < 3840; i += 256) {
        int s = i >> 6, u = i & 63;
        ybT[u * 72 + s] = y[((size_t)(b * 60 + s) * 400 + n) * 64 + u];
    }
    for (int i = tid; i < 3600; i += 256) {
        int s = i / 60, t = i - s * 60;
        kerT[t * 72 + s] = f2b(ker[b * 3600 + s * 60 + t]);
    }
    __syncthreads();

    f32x4 tacc[2][2];
#pragma unroll
    for (int a = 0; a < 2; ++a)
#pragma unroll
        for (int c = 0; c < 2; ++c) tacc[a][c] = (f32x4){0.f, 0.f, 0.f, 0.f};
#pragma unroll
    for (int k0 = 0; k0 < 64; k0 += 32) {
        short8 afr[2], bfr[2];
#pragma unroll
        for (int mt = 0; mt < 2; ++mt)
            afr[mt] = *(const short8*)&kerT[(hm * 32 + mt * 16 + m) * 72 + k0 + quad * 8];
#pragma unroll
        for (int nt = 0; nt < 2; ++nt)
            bfr[nt] = *(const short8*)&ybT[(hn * 32 + nt * 16 + m) * 72 + k0 + quad * 8];
#pragma unroll
        for (int mt = 0; mt < 2; ++mt)
#pragma unroll
            for (int nt = 0; nt < 2; ++nt)
                tacc[mt][nt] = __builtin_amdgcn_mfma_f32_16x16x32_bf16(
                    afr[mt], bfr[nt], tacc[mt][nt], 0, 0, 0);
    }
    __syncthreads();

#pragma unroll
    for (int mt = 0; mt < 2; ++mt)
#pragma unroll
        for (int nt = 0; nt < 2; ++nt)
#pragma unroll
            for (int r = 0; r < 4; ++r) {
                int t = hm * 32 + mt * 16 + quad * 4 + r;
                int u = hn * 32 + nt * 16 + m;
                if (t < 60) In[(t + 5) * 136 + u] = f2b(tacc[mt][nt][r]);
            }
    __syncthreads();

    f32x4 acc[2][2];
#pragma unroll
    for (int a = 0; a < 2; ++a)
#pragma unroll
        for (int c = 0; c < 2; ++c) acc[a][c] = (f32x4){0.f, 0.f, 0.f, 0.f};

    const short* kt0 = KT + (size_t)(hn * 32 + m) * 1536 + quad * 8;
    const short* kt1 = KT + (size_t)(hn * 32 + 16 + m) * 1536 + quad * 8;

#pragma unroll 4
    for (int kk = 0; kk < 1536; kk += 32) {
        int dt = kk >> 7, c0 = (kk & 127) + quad * 8;
        short8 a0 = *(const short8*)&In[(hm * 32 + m + dt) * 136 + c0];
        short8 a1 = *(const short8*)&In[(hm * 32 + 16 + m + dt) * 136 + c0];
        short8 b0 = *(const short8*)(kt0 + kk);
        short8 b1 = *(const short8*)(kt1 + kk);
        acc[0][0] = __builtin_amdgcn_mfma_f32_16x16x32_bf16(a0, b0, acc[0][0], 0, 0, 0);
        acc[0][1] = __builtin_amdgcn_mfma_f32_16x16x32_bf16(a0, b1, acc[0][1], 0, 0, 0);
        acc[1][0] = __builtin_amdgcn_mfma_f32_16x16x32_bf16(a1, b0, acc[1][0], 0, 0, 0);
        acc[1][1] = __builtin_amdgcn_mfma_f32_16x16x32_bf16(a1, b1, acc[1][1], 0, 0, 0);
    }

    float bias[2];
#pragma unroll
    for (int nt = 0; nt < 2; ++nt) {
        int u = hn * 32 + nt * 16 + m;
        bias[nt] = tb[u] + rb[u];
    }
#pragma unroll
    for (int mt = 0; mt < 2; ++mt)
#pragma unroll
        for (int r = 0; r < 4; ++r) {
            int t = hm * 32 + mt * 16 + quad * 4 + r;
            if (t >= 60) continue;
#pragma unroll
            for (int nt = 0; nt < 2; ++nt) {
                int u = hn * 32 + nt * 16 + m;
                float v = acc[mt][nt][r] + bias[nt];
                float sp = fmaxf(v, 0.f) + log1pf(__expf(-fabsf(v)));
                out[((size_t)(b * 60 + t) * 400 + n) * 64 + u] = sp;
            }
        }
}

// ---------------------------------------------------------------------------
extern "C" void kernel_launch(void* const* d_in, const int* in_sizes, int n_in,
                              void* d_out, int out_size, void* d_ws, size_t ws_size,
                              hipStream_t stream)
{
    const float* x    = (const float*)d_in[0];
    const float* A    = (const float*)d_in[1];
    const float* W1   = (const float*)d_in[2];
    const float* W2   = (const float*)d_in[3];
    const float* W3   = (const float*)d_in[4];
    const float* b1   = (const float*)d_in[5];
    const float* b2   = (const float*)d_in[6];
    const float* taW1 = (const float*)d_in[7];
    const float* taW2 = (const float*)d_in[8];
    const float* taW3 = (const float*)d_in[9];
    const float* Ve   = (const float*)d_in[10];
    const float* be   = (const float*)d_in[11];
    const float* tk   = (const float*)d_in[12];
    const float* tb   = (const float*)d_in[13];
    const float* rk   = (const float*)d_in[14];
    const float* rb   = (const float*)d_in[15];
    float* out = (float*)d_out;

    char* wsb = (char*)d_ws;
    size_t off = 0;
    auto alloc = [&](size_t bytes) -> void* {
        void* p = wsb + off;
        off += (bytes + 255) & ~(size_t)255;
        return p;
    };
    short* AWT           = (short*)alloc((size_t)448 * 416 * 2);
    short* W2Tb          = (short*)alloc((size_t)400 * 64 * 2);
    short* W3Tb          = (short*)alloc((size_t)64 * 64 * 2);
    unsigned char* AbT   = (unsigned char*)alloc((size_t)400 * 448);
    short* xTb           = (short*)alloc((size_t)480 * 64 * 416 * 2);
    unsigned char* xT8   = (unsigned char*)alloc((size_t)480 * 64 * 416);
    short* y             = (short*)alloc((size_t)480 * 400 * 64 * 2);
    float* r1            = (float*)alloc(480 * 64 * 4);
    float* rhs           = (float*)alloc(480 * 400 * 4);
    float* lhs           = (float*)alloc(480 * 400 * 4);
    float* Sbuf          = (float*)alloc(8 * 3600 * 4);
    float* ker           = (float*)alloc(8 * 3600 * 4);
    short* KT            = (short*)alloc((size_t)64 * 1536 * 2);

    prep_w<<<1544, 256, 0, stream>>>(A, W1, W2, W3, AWT, W2Tb, W3Tb, AbT);
    prep_xt<<<480, 256, 0, stream>>>(x, xTb, xT8);
    dgc_mfma<<<dim3(480, 7), 256, 0, stream>>>(b1, b2, (const unsigned*)AbT,
                                               AWT, W2Tb, W3Tb, xTb, xT8, y);
    ta_r1_rhs<<<480, 256, 0, stream>>>(y, taW1, taW3, r1, rhs);
    ta_lhs<<<480, 256, 0, stream>>>(r1, taW2, lhs);
    ta_product<<<dim3(15, 8), 256, 0, stream>>>(lhs, rhs, be, Sbuf);
    ta_softmax<<<8, 256, 0, stream>>>(Sbuf, Ve, ker);
    kt_prep<<<384, 256, 0, stream>>>(tk, rk, KT);
    fused_conv<<<dim3(400, 8), 256, 0, stream>>>(y, ker, x, KT, tb, rb, out);
}

// Round 5
// 502.475 us; speedup vs baseline: 1.3308x; 1.3308x over previous
//
#include <hip/hip_runtime.h>
#include <hip/hip_bf16.h>

typedef __attribute__((ext_vector_type(8))) short short8;   // 8 bf16 (4 VGPRs)
typedef __attribute__((ext_vector_type(4))) short short4_t; // 8 B
typedef __attribute__((ext_vector_type(4))) float f32x4;    // MFMA 16x16 acc

union S8u { short8 v; short4_t h[2]; };

static __device__ __forceinline__ short f2b(float f) {
    union { float f; unsigned u; } v; v.f = f;
    unsigned r = v.u + 0x7FFFu + ((v.u >> 16) & 1u);   // RNE
    return (short)(r >> 16);
}
static __device__ __forceinline__ float b2f(short s) {
    union { unsigned u; float f; } v;
    v.u = ((unsigned)(unsigned short)s) << 16;
    return v.f;
}
static __device__ __forceinline__ unsigned char f2fp8(float f) {
    return (unsigned char)(__builtin_amdgcn_cvt_pk_fp8_f32(f, f, 0, false) & 0xff);
}

// ---------------------------------------------------------------------------
// prep_w: fragment-linear weight buffers.
//  AWF  [28 g][13 kt][64 lane][8]  bf16: AWT[m=g*16+lm][n=kt*32+quad*8+j]
//  W2F  [25 jt][2 kh][64 lane][8]  bf16: W2[f=kh*32+quad*8+j][j_col=jt*16+lm]
//  W3F  [4 ut][2 kh][64 lane][8]   bf16: W3[f=kh*32+quad*8+j][u=ut*16+lm]
//  AbT  [400 j][448 m] bytes: A[m][j] != 0
// grid: 1544 x 256 = 395264 = 186368 + 25600 + 4096 + 179200
// ---------------------------------------------------------------------------
__global__ __launch_bounds__(256) void prep_w(
    const float* __restrict__ A, const float* __restrict__ W1,
    const float* __restrict__ W2, const float* __restrict__ W3,
    short* __restrict__ AWF, short* __restrict__ W2F,
    short* __restrict__ W3F, unsigned char* __restrict__ AbT)
{
    int i = blockIdx.x * 256 + threadIdx.x;
    if (i < 186368) {
        int j = i & 7, lane = (i >> 3) & 63, tile = i >> 9;
        int kt = tile % 13, g = tile / 13;
        int m = g * 16 + (lane & 15);
        int n = kt * 32 + (lane >> 4) * 8 + j;
        AWF[i] = (m < 400 && n < 400) ? f2b(A[n * 400 + m] * W1[n * 400 + m])
                                      : (short)0;
    } else if (i < 211968) {
        int o = i - 186368;
        int j = o & 7, lane = (o >> 3) & 63, tile = o >> 9;   // tile = jt*2+kh
        int kh = tile & 1, jt = tile >> 1;
        int f = kh * 32 + (lane >> 4) * 8 + j;
        int jc = jt * 16 + (lane & 15);
        W2F[o] = f2b(W2[f * 400 + jc]);
    } else if (i < 216064) {
        int o = i - 211968;
        int j = o & 7, lane = (o >> 3) & 63, tile = o >> 9;   // tile = ut*2+kh
        int kh = tile & 1, ut = tile >> 1;
        int f = kh * 32 + (lane >> 4) * 8 + j;
        int u = ut * 16 + (lane & 15);
        W3F[o] = f2b(W3[f * 64 + u]);
    } else {
        int o = i - 216064;
        int j = o / 448, m = o - j * 448;
        AbT[o] = (m < 400 && A[m * 400 + j] != 0.f) ? 1 : 0;
    }
}

// ---------------------------------------------------------------------------
// prep_xt: xF[bt][52 tiles][64 lane][8] bf16 + xF8 (fp8, same order), where
// tile = kt*4+ft holds x[n=kt*32+quad*8+j][f=ft*16+lm]. Per 64-n chunk c, the
// output range is exactly [c*4096, c*4096 + wcnt) — writes fully coalesced.
// ---------------------------------------------------------------------------
__global__ __launch_bounds__(256) void prep_xt(
    const float* __restrict__ x, short* __restrict__ xF,
    unsigned char* __restrict__ xF8)
{
    int bt = blockIdx.x, tid = threadIdx.x;
    __shared__ float tile[64][65];
    const float* xs = x + (size_t)bt * 25600;
    short* xo = xF + (size_t)bt * 26624;
    unsigned char* x8 = xF8 + (size_t)bt * 26624;
    for (int c = 0; c < 7; ++c) {
        int n0 = c * 64, cnt = (c == 6) ? 16 : 64;
        __syncthreads();
        for (int i = tid; i < cnt * 64; i += 256) {
            int r = i >> 6, f = i & 63;
            tile[r][f] = xs[(size_t)(n0 + r) * 64 + f];
        }
        __syncthreads();
        int wcnt = (c == 6) ? 2048 : 4096;     // c=6 has only kt=12
        for (int i = tid; i < wcnt; i += 256) {
            int j = i & 7, lane = (i >> 3) & 63, tl = i >> 9;
            int kt = 2 * c + (tl >> 2), ft = tl & 3;
            int n = kt * 32 + (lane >> 4) * 8 + j;
            int f = ft * 16 + (lane & 15);
            float v = (n < 400) ? tile[n - n0][f] : 0.f;
            int o = c * 4096 + i;
            xo[o] = f2b(v);
            x8[o] = f2fp8(v);
        }
    }
}

// ---------------------------------------------------------------------------
// dgc_mfma v3: barrier-free, all operand loads COALESCED (fragment-linear
// global buffers). grid (480 bt, 7 mt), 4 waves; wave w owns rows
// [mt*64+w*16, +16), g = mt*4+w.
// LDS: attnS8 64x440 fp8 (28160 B, 2-way-free b64 reads) + featS 64x72 bf16.
// ---------------------------------------------------------------------------
__global__ __launch_bounds__(256, 4) void dgc_mfma(
    const float* __restrict__ b1p, const float* __restrict__ b2p,
    const unsigned* __restrict__ AbT32,
    const short* __restrict__ AWF, const short* __restrict__ W2F,
    const short* __restrict__ W3F, const short* __restrict__ xF,
    const unsigned char* __restrict__ xF8,
    short* __restrict__ y)
{
    int bt = blockIdx.x, mt = blockIdx.y;
    int tid = threadIdx.x, lane = tid & 63, w = tid >> 6;
    int lm = lane & 15, quad = lane >> 4;

    __shared__ __align__(16) char  attnS8[64 * 440];
    __shared__ __align__(16) short featS[64 * 72];

    // zero own strip's pad cols [400,440) — wave-private, no barrier
    {
        int row = w * 16 + lm;
        *(long*)&attnS8[row * 440 + 400 + quad * 8] = 0;
        if (quad == 0) *(long*)&attnS8[row * 440 + 432] = 0;
    }

    const short* xt = xF + (size_t)bt * 26624;
    const unsigned char* xt8 = xF8 + (size_t)bt * 26624;
    int g = mt * 4 + w;

    // ---- Phase A: feat stripe [16 x 64] = AWT @ x (bf16, coalesced) ----
    f32x4 fa[4];
#pragma unroll
    for (int i = 0; i < 4; ++i) fa[i] = (f32x4){0.f, 0.f, 0.f, 0.f};
    const short* awf = AWF + (size_t)g * 13 * 512 + lane * 8;
#pragma unroll
    for (int kt = 0; kt < 13; ++kt) {
        short8 af = *(const short8*)(awf + kt * 512);
#pragma unroll
        for (int ft = 0; ft < 4; ++ft) {
            short8 bf = *(const short8*)(xt + (kt * 4 + ft) * 512 + lane * 8);
            fa[ft] = __builtin_amdgcn_mfma_f32_16x16x32_bf16(af, bf, fa[ft], 0, 0, 0);
        }
    }
#pragma unroll
    for (int ft = 0; ft < 4; ++ft)
#pragma unroll
        for (int r = 0; r < 4; ++r)
            featS[(w * 16 + quad * 4 + r) * 72 + ft * 16 + lm] = f2b(fa[ft][r]);

    // ---- Phase B: dense stripe [16 x 400] = feat @ W2, mask, softmax ----
    f32x4 da[25];
#pragma unroll
    for (int jt = 0; jt < 25; ++jt) da[jt] = (f32x4){0.f, 0.f, 0.f, 0.f};
    short8 a0 = *(const short8*)&featS[(w * 16 + lm) * 72 + quad * 8];
    short8 a1 = *(const short8*)&featS[(w * 16 + lm) * 72 + 32 + quad * 8];
#pragma unroll
    for (int jt = 0; jt < 25; ++jt) {
        short8 bf0 = *(const short8*)(W2F + (jt * 2 + 0) * 512 + lane * 8);
        short8 bf1 = *(const short8*)(W2F + (jt * 2 + 1) * 512 + lane * 8);
        da[jt] = __builtin_amdgcn_mfma_f32_16x16x32_bf16(a0, bf0, da[jt], 0, 0, 0);
        da[jt] = __builtin_amdgcn_mfma_f32_16x16x32_bf16(a1, bf1, da[jt], 0, 0, 0);
    }
    int mrb = mt * 64 + w * 16 + quad * 4;          // 4-aligned
#pragma unroll
    for (int jt = 0; jt < 25; ++jt) {
        float b1v = b1p[jt * 16 + lm];
        unsigned mv = AbT32[(size_t)(jt * 16 + lm) * 112 + (mrb >> 2)];
#pragma unroll
        for (int r = 0; r < 4; ++r) {
            float e = ((mv >> (8 * r)) & 255u) ? __expf(da[jt][r] + b1v) : 0.f;
            da[jt][r] = e;
        }
    }
    float inv_s[4];
#pragma unroll
    for (int r = 0; r < 4; ++r) {
        float s = 0.f;
#pragma unroll
        for (int jt = 0; jt < 25; ++jt) s += da[jt][r];
        s += __shfl_xor(s, 1);
        s += __shfl_xor(s, 2);
        s += __shfl_xor(s, 4);
        s += __shfl_xor(s, 8);
        inv_s[r] = 1.f / s;
    }
#pragma unroll
    for (int jt = 0; jt < 25; ++jt)
#pragma unroll
        for (int r = 0; r < 4; ++r)
            attnS8[(w * 16 + quad * 4 + r) * 440 + jt * 16 + lm] =
                (char)f2fp8(da[jt][r] * inv_s[r]);

    // ---- Phase D: nodef stripe [16 x 64] = attn @ x (fp8 MFMA) ----
    f32x4 na[4];
#pragma unroll
    for (int i = 0; i < 4; ++i) na[i] = (f32x4){0.f, 0.f, 0.f, 0.f};
    const char* at_row = attnS8 + (w * 16 + lm) * 440 + quad * 8;
#pragma unroll
    for (int kt = 0; kt < 13; ++kt) {
        long af8 = *(const long*)(at_row + kt * 32);
#pragma unroll
        for (int ft = 0; ft < 4; ++ft) {
            long bf8 = *(const long*)(xt8 + (kt * 4 + ft) * 512 + lane * 8);
            na[ft] = __builtin_amdgcn_mfma_f32_16x16x32_fp8_fp8(af8, bf8, na[ft], 0, 0, 0);
        }
    }
    // reuse featS (wave-private strip) for nodef
#pragma unroll
    for (int ft = 0; ft < 4; ++ft)
#pragma unroll
        for (int r = 0; r < 4; ++r)
            featS[(w * 16 + quad * 4 + r) * 72 + ft * 16 + lm] = f2b(na[ft][r]);

    // ---- Phase E: y stripe [16 x 64] = nodef @ W3 + b2 (bf16 out) ----
    f32x4 ya[4];
#pragma unroll
    for (int i = 0; i < 4; ++i) ya[i] = (f32x4){0.f, 0.f, 0.f, 0.f};
    short8 n0 = *(const short8*)&featS[(w * 16 + lm) * 72 + quad * 8];
    short8 n1 = *(const short8*)&featS[(w * 16 + lm) * 72 + 32 + quad * 8];
#pragma unroll
    for (int ut = 0; ut < 4; ++ut) {
        short8 bf0 = *(const short8*)(W3F + (ut * 2 + 0) * 512 + lane * 8);
        short8 bf1 = *(const short8*)(W3F + (ut * 2 + 1) * 512 + lane * 8);
        ya[ut] = __builtin_amdgcn_mfma_f32_16x16x32_bf16(n0, bf0, ya[ut], 0, 0, 0);
        ya[ut] = __builtin_amdgcn_mfma_f32_16x16x32_bf16(n1, bf1, ya[ut], 0, 0, 0);
    }
#pragma unroll
    for (int ut = 0; ut < 4; ++ut) {
        int u = ut * 16 + lm;
        float b2v = b2p[u];
#pragma unroll
        for (int r = 0; r < 4; ++r) {
            int mrow = mrb + r;
            if (mrow < 400)
                y[((size_t)bt * 400 + mrow) * 64 + u] = f2b(ya[ut][r] + b2v);
        }
    }
}

// ---------------------------------------------------------------------------
// ta_r1_rhs (y bf16): r1[bt,f]=sum_n y*taW1[n]; rhs[bt,n]=sum_f y*taW3[f]
// ---------------------------------------------------------------------------
__global__ __launch_bounds__(256) void ta_r1_rhs(
    const short* __restrict__ y, const float* __restrict__ taW1,
    const float* __restrict__ taW3, float* __restrict__ r1,
    float* __restrict__ rhs)
{
    int bt = blockIdx.x;
    const short* ys = y + (size_t)bt * 25600;
    int tid = threadIdx.x, lane = tid & 63, w = tid >> 6;
    __shared__ __align__(16) float part[4][64];
    __shared__ __align__(16) float w3s[64];
    if (tid < 64) w3s[tid] = taW3[tid];
    float acc = 0.f;
    for (int n = w * 100; n < w * 100 + 100; ++n)
        acc += taW1[n] * b2f(ys[(size_t)n * 64 + lane]);
    part[w][lane] = acc;
    __syncthreads();
    if (w == 0)
        r1[bt * 64 + lane] = part[0][lane] + part[1][lane] + part[2][lane] + part[3][lane];
    for (int n = tid; n < 400; n += 256) {
        const short8* yr = (const short8*)(ys + (size_t)n * 64);
        float a = 0.f;
#pragma unroll
        for (int q = 0; q < 8; ++q) {
            short8 v = yr[q];
#pragma unroll
            for (int e = 0; e < 8; ++e) a += b2f(v[e]) * w3s[q * 8 + e];
        }
        rhs[bt * 400 + n] = a;
    }
}

// ---------------------------------------------------------------------------
// ta_lhs: lhs[bt,n] = sum_f r1[bt,f] * taW2[f,n]
// ---------------------------------------------------------------------------
__global__ __launch_bounds__(256) void ta_lhs(
    const float* __restrict__ r1, const float* __restrict__ taW2,
    float* __restrict__ lhs)
{
    int bt = blockIdx.x, tid = threadIdx.x;
    __shared__ float r1s[64];
    if (tid < 64) r1s[tid] = r1[bt * 64 + tid];
    __syncthreads();
    for (int n = tid; n < 400; n += 256) {
        float acc = 0.f;
#pragma unroll 8
        for (int f = 0; f < 64; ++f) acc += r1s[f] * taW2[f * 400 + n];
        lhs[bt * 400 + n] = acc;
    }
}

// ---------------------------------------------------------------------------
// ta_product: S[b,k,l] = sigmoid( lhs[b,k,:].rhs[b,l,:] + be[k,l] )
// ---------------------------------------------------------------------------
__global__ __launch_bounds__(256) void ta_product(
    const float* __restrict__ lhs, const float* __restrict__ rhs,
    const float* __restrict__ be, float* __restrict__ S)
{
    int kc = blockIdx.x, b = blockIdx.y, tid = threadIdx.x;
    if (tid >= 240) return;
    int k = kc * 4 + tid / 60;
    int l = tid % 60;
    const float4* lr = (const float4*)(lhs + (size_t)(b * 60 + k) * 400);
    const float4* rr = (const float4*)(rhs + (size_t)(b * 60 + l) * 400);
    float acc = 0.f;
    for (int q = 0; q < 100; ++q) {
        float4 a = lr[q], c = rr[q];
        acc += a.x * c.x + a.y * c.y + a.z * c.z + a.w * c.w;
    }
    float v = acc + be[k * 60 + l];
    S[b * 3600 + k * 60 + l] = 1.f / (1.f + __expf(-v));
}

// ---------------------------------------------------------------------------
// ta_softmax: E[b,j,l] = sum_k Ve[j,k]*S[b,k,l]; ker = softmax over j.
// ---------------------------------------------------------------------------
__global__ __launch_bounds__(256) void ta_softmax(
    const float* __restrict__ S, const float* __restrict__ Ve,
    float* __restrict__ ker)
{
    int b = blockIdx.x, tid = threadIdx.x;
    __shared__ float Ss[3600];
    __shared__ float Emat[3600];
    for (int i = tid; i < 3600; i += 256) Ss[i] = S[b * 3600 + i];
    __syncthreads();
    for (int p = tid; p < 3600; p += 256) {
        int j = p / 60, l = p % 60;
        float acc = 0.f;
        for (int k = 0; k < 60; ++k) acc += Ve[j * 60 + k] * Ss[k * 60 + l];
        Emat[p] = acc;
    }
    __syncthreads();
    for (int l = tid; l < 60; l += 256) {
        float mx = -1e30f;
        for (int j = 0; j < 60; ++j) mx = fmaxf(mx, Emat[j * 60 + l]);
        float s = 0.f;
        for (int j = 0; j < 60; ++j) s += __expf(Emat[j * 60 + l] - mx);
        float inv = 1.f / s;
        for (int j = 0; j < 60; ++j)
            ker[b * 3600 + j * 60 + l] = __expf(Emat[j * 60 + l] - mx) * inv;
    }
}

// ---------------------------------------------------------------------------
// ktf_prep: fragment-linear conv weights.
// KTF[4 ng][48 kkt][64 lane][8] bf16: tile ng = hn*2+nt holds
//   K[kk = kkt*32+quad*8+j][u = hn*32+nt*16+lm], K = [tk ; rk] along c.
// 98304 elems, 384 blocks.
// ---------------------------------------------------------------------------
__global__ __launch_bounds__(256) void ktf_prep(
    const float* __restrict__ tk, const float* __restrict__ rk,
    short* __restrict__ KTF)
{
    int i = blockIdx.x * 256 + threadIdx.x;      // [0, 98304)
    int j = i & 7, lane = (i >> 3) & 63, tile = i >> 9;   // tile in [0,192)
    int kkt = tile % 48, ng = tile / 48;
    int u = (ng >> 1) * 32 + (ng & 1) * 16 + (lane & 15);
    int kk = kkt * 32 + (lane >> 4) * 8 + j;
    int dt = kk >> 7, c = kk & 127;
    float v = (c < 64) ? tk[dt * 4096 + c * 64 + u]
                       : rk[dt * 4096 + (c - 64) * 64 + u];
    KTF[i] = f2b(v);
}

// ---------------------------------------------------------------------------
// fused_conv: time-mix + both temporal convs + softplus, bf16 MFMA.
// KTF loads coalesced; In stride 132 shorts (4-way banks, short4-pair loads).
// ---------------------------------------------------------------------------
#define IN_S 132
__global__ __launch_bounds__(256, 4) void fused_conv(
    const short* __restrict__ y, const float* __restrict__ ker,
    const float* __restrict__ x, const short* __restrict__ KTF,
    const float* __restrict__ tb, const float* __restrict__ rb,
    float* __restrict__ out)
{
    int n = blockIdx.x, b = blockIdx.y;
    int tid = threadIdx.x, lane = tid & 63, w = tid >> 6;
    int m = lane & 15, quad = lane >> 4;
    int hm = w >> 1, hn = w & 1;

    __shared__ __align__(16) short In[75 * IN_S];
    __shared__ __align__(16) short kerT[64 * 72];
    __shared__ __align__(16) short ybT[64 * 72];

    for (int i = tid; i < 75 * IN_S; i += 256) In[i] = 0;
    for (int i = tid; i < 64 * 72; i += 256) { kerT[i] = 0; ybT[i] = 0; }
    __syncthreads();

    for (int i = tid; i < 3840; i += 256) {
        int t = i >> 6, u = i & 63;
        In[(t + 5) * IN_S + 64 + u] = f2b(x[((size_t)(b * 60 + t) * 400 + n) * 64 + u]);
    }
    for (int i = tid; i < 3840; i += 256) {
        int s = i >> 6, u = i & 63;
        ybT[u * 72 + s] = y[((size_t)(b * 60 + s) * 400 + n) * 64 + u];
    }
    for (int i = tid; i < 3600; i += 256) {
        int s = i / 60, t = i - s * 60;
        kerT[t * 72 + s] = f2b(ker[b * 3600 + s * 60 + t]);
    }
    __syncthreads();

    // ---- time-mix GEMM (M=64,N=64,K=64) ----
    f32x4 tacc[2][2];
#pragma unroll
    for (int a = 0; a < 2; ++a)
#pragma unroll
        for (int c = 0; c < 2; ++c) tacc[a][c] = (f32x4){0.f, 0.f, 0.f, 0.f};
#pragma unroll
    for (int k0 = 0; k0 < 64; k0 += 32) {
        short8 afr[2], bfr[2];
#pragma unroll
        for (int mt = 0; mt < 2; ++mt)
            afr[mt] = *(const short8*)&kerT[(hm * 32 + mt * 16 + m) * 72 + k0 + quad * 8];
#pragma unroll
        for (int nt = 0; nt < 2; ++nt)
            bfr[nt] = *(const short8*)&ybT[(hn * 32 + nt * 16 + m) * 72 + k0 + quad * 8];
#pragma unroll
        for (int mt = 0; mt < 2; ++mt)
#pragma unroll
            for (int nt = 0; nt < 2; ++nt)
                tacc[mt][nt] = __builtin_amdgcn_mfma_f32_16x16x32_bf16(
                    afr[mt], bfr[nt], tacc[mt][nt], 0, 0, 0);
    }
    __syncthreads();

#pragma unroll
    for (int mt = 0; mt < 2; ++mt)
#pragma unroll
        for (int nt = 0; nt < 2; ++nt)
#pragma unroll
            for (int r = 0; r < 4; ++r) {
                int t = hm * 32 + mt * 16 + quad * 4 + r;
                int u = hn * 32 + nt * 16 + m;
                if (t < 60) In[(t + 5) * IN_S + u] = f2b(tacc[mt][nt][r]);
            }
    __syncthreads();

    // ---- conv GEMM (M=64,N=64,K=1536): A from LDS, B from global KTF ----
    f32x4 acc[2][2];
#pragma unroll
    for (int a = 0; a < 2; ++a)
#pragma unroll
        for (int c = 0; c < 2; ++c) acc[a][c] = (f32x4){0.f, 0.f, 0.f, 0.f};

    const short* ktf0 = KTF + (size_t)(hn * 2 + 0) * 48 * 512 + lane * 8;
    const short* ktf1 = KTF + (size_t)(hn * 2 + 1) * 48 * 512 + lane * 8;

#pragma unroll 4
    for (int kkt = 0; kkt < 48; ++kkt) {
        int kk = kkt * 32;
        int dt = kk >> 7, c0 = (kk & 127) + quad * 8;
        int i0 = (hm * 32 + m + dt) * IN_S + c0;
        int i1 = i0 + 16 * IN_S;
        S8u a0, a1;
        a0.h[0] = *(const short4_t*)&In[i0];
        a0.h[1] = *(const short4_t*)&In[i0 + 4];
        a1.h[0] = *(const short4_t*)&In[i1];
        a1.h[1] = *(const short4_t*)&In[i1 + 4];
        short8 b0 = *(const short8*)(ktf0 + kkt * 512);
        short8 b1 = *(const short8*)(ktf1 + kkt * 512);
        acc[0][0] = __builtin_amdgcn_mfma_f32_16x16x32_bf16(a0.v, b0, acc[0][0], 0, 0, 0);
        acc[0][1] = __builtin_amdgcn_mfma_f32_16x16x32_bf16(a0.v, b1, acc[0][1], 0, 0, 0);
        acc[1][0] = __builtin_amdgcn_mfma_f32_16x16x32_bf16(a1.v, b0, acc[1][0], 0, 0, 0);
        acc[1][1] = __builtin_amdgcn_mfma_f32_16x16x32_bf16(a1.v, b1, acc[1][1], 0, 0, 0);
    }

    float bias[2];
#pragma unroll
    for (int nt = 0; nt < 2; ++nt) {
        int u = hn * 32 + nt * 16 + m;
        bias[nt] = tb[u] + rb[u];
    }
#pragma unroll
    for (int mt = 0; mt < 2; ++mt)
#pragma unroll
        for (int r = 0; r < 4; ++r) {
            int t = hm * 32 + mt * 16 + quad * 4 + r;
            if (t >= 60) continue;
#pragma unroll
            for (int nt = 0; nt < 2; ++nt) {
                int u = hn * 32 + nt * 16 + m;
                float v = acc[mt][nt][r] + bias[nt];
                float sp = fmaxf(v, 0.f) + log1pf(__expf(-fabsf(v)));
                out[((size_t)(b * 60 + t) * 400 + n) * 64 + u] = sp;
            }
        }
}

// ---------------------------------------------------------------------------
extern "C" void kernel_launch(void* const* d_in, const int* in_sizes, int n_in,
                              void* d_out, int out_size, void* d_ws, size_t ws_size,
                              hipStream_t stream)
{
    const float* x    = (const float*)d_in[0];
    const float* A    = (const float*)d_in[1];
    const float* W1   = (const float*)d_in[2];
    const float* W2   = (const float*)d_in[3];
    const float* W3   = (const float*)d_in[4];
    const float* b1   = (const float*)d_in[5];
    const float* b2   = (const float*)d_in[6];
    const float* taW1 = (const float*)d_in[7];
    const float* taW2 = (const float*)d_in[8];
    const float* taW3 = (const float*)d_in[9];
    const float* Ve   = (const float*)d_in[10];
    const float* be   = (const float*)d_in[11];
    const float* tk   = (const float*)d_in[12];
    const float* tb   = (const float*)d_in[13];
    const float* rk   = (const float*)d_in[14];
    const float* rb   = (const float*)d_in[15];
    float* out = (float*)d_out;

    char* wsb = (char*)d_ws;
    size_t off = 0;
    auto alloc = [&](size_t bytes) -> void* {
        void* p = wsb + off;
        off += (bytes + 255) & ~(size_t)255;
        return p;
    };
    short* AWF           = (short*)alloc((size_t)186368 * 2);
    short* W2F           = (short*)alloc((size_t)25600 * 2);
    short* W3F           = (short*)alloc((size_t)4096 * 2);
    unsigned char* AbT   = (unsigned char*)alloc((size_t)400 * 448);
    short* xF            = (short*)alloc((size_t)480 * 26624 * 2);
    unsigned char* xF8   = (unsigned char*)alloc((size_t)480 * 26624);
    short* y             = (short*)alloc((size_t)480 * 400 * 64 * 2);
    float* r1            = (float*)alloc(480 * 64 * 4);
    float* rhs           = (float*)alloc(480 * 400 * 4);
    float* lhs           = (float*)alloc(480 * 400 * 4);
    float* Sbuf          = (float*)alloc(8 * 3600 * 4);
    float* ker           = (float*)alloc(8 * 3600 * 4);
    short* KTF           = (short*)alloc((size_t)98304 * 2);

    prep_w<<<1544, 256, 0, stream>>>(A, W1, W2, W3, AWF, W2F, W3F, AbT);
    prep_xt<<<480, 256, 0, stream>>>(x, xF, xF8);
    dgc_mfma<<<dim3(480, 7), 256, 0, stream>>>(b1, b2, (const unsigned*)AbT,
                                               AWF, W2F, W3F, xF, xF8, y);
    ta_r1_rhs<<<480, 256, 0, stream>>>(y, taW1, taW3, r1, rhs);
    ta_lhs<<<480, 256, 0, stream>>>(r1, taW2, lhs);
    ta_product<<<dim3(15, 8), 256, 0, stream>>>(lhs, rhs, be, Sbuf);
    ta_softmax<<<8, 256, 0, stream>>>(Sbuf, Ve, ker);
    ktf_prep<<<384, 256, 0, stream>>>(tk, rk, KTF);
    fused_conv<<<dim3(400, 8), 256, 0, stream>>>(y, ker, x, KTF, tb, rb, out);
}

// Round 6
// 440.889 us; speedup vs baseline: 1.5167x; 1.1397x over previous
//
#include <hip/hip_runtime.h>
#include <hip/hip_bf16.h>

typedef __attribute__((ext_vector_type(8))) short short8;   // 8 bf16 (4 VGPRs)
typedef __attribute__((ext_vector_type(4))) short short4_t; // 8 B
typedef __attribute__((ext_vector_type(4))) float f32x4;    // MFMA 16x16 acc

union S8u { short8 v; short4_t h[2]; };
union P8u { unsigned char b[8]; long v; };

static __device__ __forceinline__ short f2b(float f) {
    union { float f; unsigned u; } v; v.f = f;
    unsigned r = v.u + 0x7FFFu + ((v.u >> 16) & 1u);   // RNE
    return (short)(r >> 16);
}
static __device__ __forceinline__ unsigned char f2fp8(float f) {
    return (unsigned char)(__builtin_amdgcn_cvt_pk_fp8_f32(f, f, 0, false) & 0xff);
}

// ---------------------------------------------------------------------------
// prep_w: fragment buffers, one THREAD per (tile,lane) -> 8 elems.
// All reads wave-coalesced (16 lanes span contiguous 64B); 16B stores.
//  tiles: [0,364) AWF  (g*13+kt):  A^T*W1^T [m=g*16+lm][n=kt*32+quad*8+j]
//         [364,414) W2F (jt*2+kh): W2[f=kh*32+quad*8+j][jc=jt*16+lm]
//         [414,422) W3F (ut*2+kh): W3[f][u=ut*16+lm]
//  then AbT[400 j][448 m] bytes.
// grid 806 x 256 (422*64 + 179200 = 206208 threads)
// ---------------------------------------------------------------------------
__global__ __launch_bounds__(256) void prep_w(
    const float* __restrict__ A, const float* __restrict__ W1,
    const float* __restrict__ W2, const float* __restrict__ W3,
    short* __restrict__ AWF, short* __restrict__ W2F,
    short* __restrict__ W3F, unsigned char* __restrict__ AbT)
{
    int t = blockIdx.x * 256 + threadIdx.x;
    if (t < 422 * 64) {
        int tile = t >> 6, lane = t & 63, lm = lane & 15, quad = lane >> 4;
        short8 o;
        if (tile < 364) {
            int kt = tile % 13, g = tile / 13;
            int m = g * 16 + lm;
#pragma unroll
            for (int j = 0; j < 8; ++j) {
                int n = kt * 32 + quad * 8 + j;
                float v = (m < 400 && n < 400) ? A[n * 400 + m] * W1[n * 400 + m] : 0.f;
                o[j] = f2b(v);
            }
            *(short8*)(AWF + tile * 512 + lane * 8) = o;
        } else if (tile < 414) {
            int t2 = tile - 364;
            int kh = t2 & 1, jt = t2 >> 1;
            int jc = jt * 16 + lm;
#pragma unroll
            for (int j = 0; j < 8; ++j) {
                int f = kh * 32 + quad * 8 + j;
                o[j] = f2b(W2[f * 400 + jc]);
            }
            *(short8*)(W2F + t2 * 512 + lane * 8) = o;
        } else {
            int t3 = tile - 414;
            int kh = t3 & 1, ut = t3 >> 1;
            int u = ut * 16 + lm;
#pragma unroll
            for (int j = 0; j < 8; ++j) {
                int f = kh * 32 + quad * 8 + j;
                o[j] = f2b(W3[f * 64 + u]);
            }
            *(short8*)(W3F + t3 * 512 + lane * 8) = o;
        }
    } else {
        int o = t - 27008;
        if (o < 179200) {
            int j = o / 448, m = o - j * 448;
            AbT[o] = (m < 400 && A[m * 400 + j] != 0.f) ? 1 : 0;
        }
    }
}

// ---------------------------------------------------------------------------
// prep_xt: xF / xF8 fragment-linear, no LDS. One wave per tile; thread
// gathers 8 elems via 8 wave-coalesced dword loads, writes 16B + 8B.
// grid 480*13 blocks; block = (bt, kt), 4 waves = ft 0..3.
// ---------------------------------------------------------------------------
__global__ __launch_bounds__(256) void prep_xt(
    const float* __restrict__ x, short* __restrict__ xF,
    unsigned char* __restrict__ xF8)
{
    int bt = blockIdx.x / 13, kt = blockIdx.x % 13;
    int tid = threadIdx.x, lane = tid & 63, ft = tid >> 6;
    int lm = lane & 15, quad = lane >> 4;
    const float* xs = x + (size_t)bt * 25600;
    int tile = kt * 4 + ft;
    int f = ft * 16 + lm;
    short8 ob; P8u p8;
#pragma unroll
    for (int j = 0; j < 8; ++j) {
        int n = kt * 32 + quad * 8 + j;
        float v = (n < 400) ? xs[(size_t)n * 64 + f] : 0.f;
        ob[j] = f2b(v);
        p8.b[j] = f2fp8(v);
    }
    size_t o = (size_t)bt * 26624 + tile * 512 + lane * 8;
    *(short8*)(xF + o) = ob;
    *(long*)(xF8 + o) = p8.v;
}

// ---------------------------------------------------------------------------
// dgc_mfma v4: batched loads (10 in flight), launch_bounds(256,2) so the
// register allocator keeps prefetch batches live (R5's (256,4) squeezed
// VGPRs to 64 and serialized every load). Epilogue also emits rhs (shuffle
// reduce) and r1 partials (atomicAdd) -> ta_r1_rhs kernel eliminated.
// grid (7 mt, 480 bt), 4 waves; wave w owns rows [mt*64+w*16, +16).
// ---------------------------------------------------------------------------
__global__ __launch_bounds__(256, 2) void dgc_mfma(
    const float* __restrict__ b1p, const float* __restrict__ b2p,
    const unsigned* __restrict__ AbT32,
    const short* __restrict__ AWF, const short* __restrict__ W2F,
    const short* __restrict__ W3F, const short* __restrict__ xF,
    const unsigned char* __restrict__ xF8,
    const float* __restrict__ taW1, const float* __restrict__ taW3,
    short* __restrict__ y, float* __restrict__ rhs, float* __restrict__ r1)
{
    int mt = blockIdx.x, bt = blockIdx.y;
    int tid = threadIdx.x, lane = tid & 63, w = tid >> 6;
    int lm = lane & 15, quad = lane >> 4;

    __shared__ __align__(16) char  attnS8[64 * 440];
    __shared__ __align__(16) short featS[64 * 72];

    {   // zero own strip's pad cols [400,440) — wave-private, no barrier
        int row = w * 16 + lm;
        *(long*)&attnS8[row * 440 + 400 + quad * 8] = 0;
        if (quad == 0) *(long*)&attnS8[row * 440 + 432] = 0;
    }

    const short* xtb = xF + (size_t)bt * 26624 + lane * 8;
    const unsigned char* xt8b = xF8 + (size_t)bt * 26624 + lane * 8;
    int g = mt * 4 + w;

    // ---- Phase A: feat stripe [16 x 64] = AWT @ x, batched 2 kt ----
    f32x4 fa[4];
#pragma unroll
    for (int i = 0; i < 4; ++i) fa[i] = (f32x4){0.f, 0.f, 0.f, 0.f};
    const short* awf = AWF + (size_t)g * 13 * 512 + lane * 8;
#pragma unroll
    for (int kb = 0; kb < 12; kb += 2) {
        short8 af0 = *(const short8*)(awf + kb * 512);
        short8 af1 = *(const short8*)(awf + (kb + 1) * 512);
        short8 bf[8];
#pragma unroll
        for (int ft = 0; ft < 4; ++ft) {
            bf[ft]     = *(const short8*)(xtb + (kb * 4 + ft) * 512);
            bf[4 + ft] = *(const short8*)(xtb + ((kb + 1) * 4 + ft) * 512);
        }
#pragma unroll
        for (int ft = 0; ft < 4; ++ft) {
            fa[ft] = __builtin_amdgcn_mfma_f32_16x16x32_bf16(af0, bf[ft], fa[ft], 0, 0, 0);
            fa[ft] = __builtin_amdgcn_mfma_f32_16x16x32_bf16(af1, bf[4 + ft], fa[ft], 0, 0, 0);
        }
    }
    {   // kt = 12 tail
        short8 af = *(const short8*)(awf + 12 * 512);
        short8 bf[4];
#pragma unroll
        for (int ft = 0; ft < 4; ++ft)
            bf[ft] = *(const short8*)(xtb + (48 + ft) * 512);
#pragma unroll
        for (int ft = 0; ft < 4; ++ft)
            fa[ft] = __builtin_amdgcn_mfma_f32_16x16x32_bf16(af, bf[ft], fa[ft], 0, 0, 0);
    }
#pragma unroll
    for (int ft = 0; ft < 4; ++ft)
#pragma unroll
        for (int r = 0; r < 4; ++r)
            featS[(w * 16 + quad * 4 + r) * 72 + ft * 16 + lm] = f2b(fa[ft][r]);

    // ---- Phase B: dense stripe [16 x 400], batched 5 jt (10 loads) ----
    f32x4 da[25];
#pragma unroll
    for (int jt = 0; jt < 25; ++jt) da[jt] = (f32x4){0.f, 0.f, 0.f, 0.f};
    short8 a0 = *(const short8*)&featS[(w * 16 + lm) * 72 + quad * 8];
    short8 a1 = *(const short8*)&featS[(w * 16 + lm) * 72 + 32 + quad * 8];
#pragma unroll
    for (int jb = 0; jb < 25; jb += 5) {
        short8 bf[10];
#pragma unroll
        for (int q = 0; q < 5; ++q) {
            bf[2 * q]     = *(const short8*)(W2F + ((jb + q) * 2 + 0) * 512 + lane * 8);
            bf[2 * q + 1] = *(const short8*)(W2F + ((jb + q) * 2 + 1) * 512 + lane * 8);
        }
#pragma unroll
        for (int q = 0; q < 5; ++q) {
            da[jb + q] = __builtin_amdgcn_mfma_f32_16x16x32_bf16(a0, bf[2 * q], da[jb + q], 0, 0, 0);
            da[jb + q] = __builtin_amdgcn_mfma_f32_16x16x32_bf16(a1, bf[2 * q + 1], da[jb + q], 0, 0, 0);
        }
    }
    int mrb = mt * 64 + w * 16 + quad * 4;          // 4-aligned
#pragma unroll
    for (int jt = 0; jt < 25; ++jt) {
        float b1v = b1p[jt * 16 + lm];
        unsigned mv = AbT32[(size_t)(jt * 16 + lm) * 112 + (mrb >> 2)];
#pragma unroll
        for (int r = 0; r < 4; ++r) {
            float e = ((mv >> (8 * r)) & 255u) ? __expf(da[jt][r] + b1v) : 0.f;
            da[jt][r] = e;
        }
    }
    float inv_s[4];
#pragma unroll
    for (int r = 0; r < 4; ++r) {
        float s = 0.f;
#pragma unroll
        for (int jt = 0; jt < 25; ++jt) s += da[jt][r];
        s += __shfl_xor(s, 1);
        s += __shfl_xor(s, 2);
        s += __shfl_xor(s, 4);
        s += __shfl_xor(s, 8);
        inv_s[r] = 1.f / s;
    }
#pragma unroll
    for (int jt = 0; jt < 25; ++jt)
#pragma unroll
        for (int r = 0; r < 4; ++r)
            attnS8[(w * 16 + quad * 4 + r) * 440 + jt * 16 + lm] =
                (char)f2fp8(da[jt][r] * inv_s[r]);

    // ---- Phase D: nodef stripe [16 x 64] = attn @ x (fp8), batched 2 kt ----
    f32x4 na[4];
#pragma unroll
    for (int i = 0; i < 4; ++i) na[i] = (f32x4){0.f, 0.f, 0.f, 0.f};
    const char* at_row = attnS8 + (w * 16 + lm) * 440 + quad * 8;
#pragma unroll
    for (int kb = 0; kb < 12; kb += 2) {
        long af0 = *(const long*)(at_row + kb * 32);
        long af1 = *(const long*)(at_row + (kb + 1) * 32);
        long bf[8];
#pragma unroll
        for (int ft = 0; ft < 4; ++ft) {
            bf[ft]     = *(const long*)(xt8b + (kb * 4 + ft) * 512);
            bf[4 + ft] = *(const long*)(xt8b + ((kb + 1) * 4 + ft) * 512);
        }
#pragma unroll
        for (int ft = 0; ft < 4; ++ft) {
            na[ft] = __builtin_amdgcn_mfma_f32_16x16x32_fp8_fp8(af0, bf[ft], na[ft], 0, 0, 0);
            na[ft] = __builtin_amdgcn_mfma_f32_16x16x32_fp8_fp8(af1, bf[4 + ft], na[ft], 0, 0, 0);
        }
    }
    {   // kt = 12 tail
        long af = *(const long*)(at_row + 12 * 32);
        long bf[4];
#pragma unroll
        for (int ft = 0; ft < 4; ++ft)
            bf[ft] = *(const long*)(xt8b + (48 + ft) * 512);
#pragma unroll
        for (int ft = 0; ft < 4; ++ft)
            na[ft] = __builtin_amdgcn_mfma_f32_16x16x32_fp8_fp8(af, bf[ft], na[ft], 0, 0, 0);
    }
#pragma unroll
    for (int ft = 0; ft < 4; ++ft)
#pragma unroll
        for (int r = 0; r < 4; ++r)
            featS[(w * 16 + quad * 4 + r) * 72 + ft * 16 + lm] = f2b(na[ft][r]);

    // ---- Phase E: y stripe [16 x 64] = nodef @ W3 + b2 ----
    f32x4 ya[4];
#pragma unroll
    for (int i = 0; i < 4; ++i) ya[i] = (f32x4){0.f, 0.f, 0.f, 0.f};
    short8 nf0 = *(const short8*)&featS[(w * 16 + lm) * 72 + quad * 8];
    short8 nf1 = *(const short8*)&featS[(w * 16 + lm) * 72 + 32 + quad * 8];
    {
        short8 wb[8];
#pragma unroll
        for (int ut = 0; ut < 4; ++ut) {
            wb[2 * ut]     = *(const short8*)(W3F + (ut * 2 + 0) * 512 + lane * 8);
            wb[2 * ut + 1] = *(const short8*)(W3F + (ut * 2 + 1) * 512 + lane * 8);
        }
#pragma unroll
        for (int ut = 0; ut < 4; ++ut) {
            ya[ut] = __builtin_amdgcn_mfma_f32_16x16x32_bf16(nf0, wb[2 * ut], ya[ut], 0, 0, 0);
            ya[ut] = __builtin_amdgcn_mfma_f32_16x16x32_bf16(nf1, wb[2 * ut + 1], ya[ut], 0, 0, 0);
        }
    }

    // ---- Epilogue: y store + rhs + r1 partials ----
    float yv[4][4];
#pragma unroll
    for (int ut = 0; ut < 4; ++ut) {
        int u = ut * 16 + lm;
        float b2v = b2p[u];
#pragma unroll
        for (int r = 0; r < 4; ++r) {
            yv[ut][r] = ya[ut][r] + b2v;
            int mrow = mrb + r;
            if (mrow < 400)
                y[((size_t)bt * 400 + mrow) * 64 + u] = f2b(yv[ut][r]);
        }
    }
    // rhs[bt, mrb+r] = sum_u yv*taW3[u] (reduce over 16 lanes of quad)
    float w3r[4];
#pragma unroll
    for (int ut = 0; ut < 4; ++ut) w3r[ut] = taW3[ut * 16 + lm];
    float rv[4];
#pragma unroll
    for (int r = 0; r < 4; ++r) {
        float v = yv[0][r] * w3r[0] + yv[1][r] * w3r[1] +
                  yv[2][r] * w3r[2] + yv[3][r] * w3r[3];
        v += __shfl_xor(v, 1);
        v += __shfl_xor(v, 2);
        v += __shfl_xor(v, 4);
        v += __shfl_xor(v, 8);
        rv[r] = v;
    }
    if (lm == 0 && mrb < 400)
        *(float4*)(rhs + (size_t)bt * 400 + mrb) = make_float4(rv[0], rv[1], rv[2], rv[3]);
    // r1[bt, u] += sum_rows yv*taW1[row] (reduce over quads, atomic)
    float p[4] = {0.f, 0.f, 0.f, 0.f};
#pragma unroll
    for (int r = 0; r < 4; ++r) {
        int mrow = mrb + r;
        if (mrow < 400) {
            float w1v = taW1[mrow];
#pragma unroll
            for (int ut = 0; ut < 4; ++ut) p[ut] += yv[ut][r] * w1v;
        }
    }
#pragma unroll
    for (int ut = 0; ut < 4; ++ut) {
        p[ut] += __shfl_xor(p[ut], 16);
        p[ut] += __shfl_xor(p[ut], 32);
    }
    if (quad == 0) {
#pragma unroll
        for (int ut = 0; ut < 4; ++ut)
            atomicAdd(&r1[bt * 64 + ut * 16 + lm], p[ut]);
    }
}

// ---------------------------------------------------------------------------
// ta_lhs: lhs[bt,n] = sum_f r1[bt,f] * taW2[f,n]
// ---------------------------------------------------------------------------
__global__ __launch_bounds__(256) void ta_lhs(
    const float* __restrict__ r1, const float* __restrict__ taW2,
    float* __restrict__ lhs)
{
    int bt = blockIdx.x, tid = threadIdx.x;
    __shared__ float r1s[64];
    if (tid < 64) r1s[tid] = r1[bt * 64 + tid];
    __syncthreads();
    for (int n = tid; n < 400; n += 256) {
        float acc = 0.f;
#pragma unroll 8
        for (int f = 0; f < 64; ++f) acc += r1s[f] * taW2[f * 400 + n];
        lhs[bt * 400 + n] = acc;
    }
}

// ---------------------------------------------------------------------------
// ta_product: S[b,k,l] = sigmoid( lhs[b,k,:].rhs[b,l,:] + be[k,l] )
// ---------------------------------------------------------------------------
__global__ __launch_bounds__(256) void ta_product(
    const float* __restrict__ lhs, const float* __restrict__ rhs,
    const float* __restrict__ be, float* __restrict__ S)
{
    int kc = blockIdx.x, b = blockIdx.y, tid = threadIdx.x;
    if (tid >= 240) return;
    int k = kc * 4 + tid / 60;
    int l = tid % 60;
    const float4* lr = (const float4*)(lhs + (size_t)(b * 60 + k) * 400);
    const float4* rr = (const float4*)(rhs + (size_t)(b * 60 + l) * 400);
    float acc = 0.f;
    for (int q = 0; q < 100; ++q) {
        float4 a = lr[q], c = rr[q];
        acc += a.x * c.x + a.y * c.y + a.z * c.z + a.w * c.w;
    }
    float v = acc + be[k * 60 + l];
    S[b * 3600 + k * 60 + l] = 1.f / (1.f + __expf(-v));
}

// ---------------------------------------------------------------------------
// ta_softmax: E[b,j,l] = sum_k Ve[j,k]*S[b,k,l]; ker = softmax over j.
// ---------------------------------------------------------------------------
__global__ __launch_bounds__(256) void ta_softmax(
    const float* __restrict__ S, const float* __restrict__ Ve,
    float* __restrict__ ker)
{
    int b = blockIdx.x, tid = threadIdx.x;
    __shared__ float Ss[3600];
    __shared__ float Emat[3600];
    for (int i = tid; i < 3600; i += 256) Ss[i] = S[b * 3600 + i];
    __syncthreads();
    for (int p = tid; p < 3600; p += 256) {
        int j = p / 60, l = p % 60;
        float acc = 0.f;
        for (int k = 0; k < 60; ++k) acc += Ve[j * 60 + k] * Ss[k * 60 + l];
        Emat[p] = acc;
    }
    __syncthreads();
    for (int l = tid; l < 60; l += 256) {
        float mx = -1e30f;
        for (int j = 0; j < 60; ++j) mx = fmaxf(mx, Emat[j * 60 + l]);
        float s = 0.f;
        for (int j = 0; j < 60; ++j) s += __expf(Emat[j * 60 + l] - mx);
        float inv = 1.f / s;
        for (int j = 0; j < 60; ++j)
            ker[b * 3600 + j * 60 + l] = __expf(Emat[j * 60 + l] - mx) * inv;
    }
}

// ---------------------------------------------------------------------------
// ktf_prep: fragment-linear conv weights (unchanged).
// ---------------------------------------------------------------------------
__global__ __launch_bounds__(256) void ktf_prep(
    const float* __restrict__ tk, const float* __restrict__ rk,
    short* __restrict__ KTF)
{
    int i = blockIdx.x * 256 + threadIdx.x;      // [0, 98304)
    int j = i & 7, lane = (i >> 3) & 63, tile = i >> 9;   // tile in [0,192)
    int kkt = tile % 48, ng = tile / 48;
    int u = (ng >> 1) * 32 + (ng & 1) * 16 + (lane & 15);
    int kk = kkt * 32 + (lane >> 4) * 8 + j;
    int dt = kk >> 7, c = kk & 127;
    float v = (c < 64) ? tk[dt * 4096 + c * 64 + u]
                       : rk[dt * 4096 + (c - 64) * 64 + u];
    KTF[i] = f2b(v);
}

// ---------------------------------------------------------------------------
// fused_conv: time-mix + both temporal convs + softplus, bf16 MFMA.
// Conv K-loop batched 2 kkt for load overlap.
// ---------------------------------------------------------------------------
#define IN_S 132
__global__ __launch_bounds__(256, 4) void fused_conv(
    const short* __restrict__ y, const float* __restrict__ ker,
    const float* __restrict__ x, const short* __restrict__ KTF,
    const float* __restrict__ tb, const float* __restrict__ rb,
    float* __restrict__ out)
{
    int n = blockIdx.x, b = blockIdx.y;
    int tid = threadIdx.x, lane = tid & 63, w = tid >> 6;
    int m = lane & 15, quad = lane >> 4;
    int hm = w >> 1, hn = w & 1;

    __shared__ __align__(16) short In[75 * IN_S];
    __shared__ __align__(16) short kerT[64 * 72];
    __shared__ __align__(16) short ybT[64 * 72];

    for (int i = tid; i < 75 * IN_S; i += 256) In[i] = 0;
    for (int i = tid; i < 64 * 72; i += 256) { kerT[i] = 0; ybT[i] = 0; }
    __syncthreads();

    for (int i = tid; i < 3840; i += 256) {
        int t = i >> 6, u = i & 63;
        In[(t + 5) * IN_S + 64 + u] = f2b(x[((size_t)(b * 60 + t) * 400 + n) * 64 + u]);
    }
    for (int i = tid; i < 3840; i += 256) {
        int s = i >> 6, u = i & 63;
        ybT[u * 72 + s] = y[((size_t)(b * 60 + s) * 400 + n) * 64 + u];
    }
    for (int i = tid; i < 3600; i += 256) {
        int s = i / 60, t = i - s * 60;
        kerT[t * 72 + s] = f2b(ker[b * 3600 + s * 60 + t]);
    }
    __syncthreads();

    // ---- time-mix GEMM (M=64,N=64,K=64) ----
    f32x4 tacc[2][2];
#pragma unroll
    for (int a = 0; a < 2; ++a)
#pragma unroll
        for (int c = 0; c < 2; ++c) tacc[a][c] = (f32x4){0.f, 0.f, 0.f, 0.f};
#pragma unroll
    for (int k0 = 0; k0 < 64; k0 += 32) {
        short8 afr[2], bfr[2];
#pragma unroll
        for (int mt = 0; mt < 2; ++mt)
            afr[mt] = *(const short8*)&kerT[(hm * 32 + mt * 16 + m) * 72 + k0 + quad * 8];
#pragma unroll
        for (int nt = 0; nt < 2; ++nt)
            bfr[nt] = *(const short8*)&ybT[(hn * 32 + nt * 16 + m) * 72 + k0 + quad * 8];
#pragma unroll
        for (int mt = 0; mt < 2; ++mt)
#pragma unroll
            for (int nt = 0; nt < 2; ++nt)
                tacc[mt][nt] = __builtin_amdgcn_mfma_f32_16x16x32_bf16(
                    afr[mt], bfr[nt], tacc[mt][nt], 0, 0, 0);
    }
    __syncthreads();

#pragma unroll
    for (int mt = 0; mt < 2; ++mt)
#pragma unroll
        for (int nt = 0; nt < 2; ++nt)
#pragma unroll
            for (int r = 0; r < 4; ++r) {
                int t = hm * 32 + mt * 16 + quad * 4 + r;
                int u = hn * 32 + nt * 16 + m;
                if (t < 60) In[(t + 5) * IN_S + u] = f2b(tacc[mt][nt][r]);
            }
    __syncthreads();

    // ---- conv GEMM (M=64,N=64,K=1536), batched 2 kkt ----
    f32x4 acc[2][2];
#pragma unroll
    for (int a = 0; a < 2; ++a)
#pragma unroll
        for (int c = 0; c < 2; ++c) acc[a][c] = (f32x4){0.f, 0.f, 0.f, 0.f};

    const short* ktf0 = KTF + (size_t)(hn * 2 + 0) * 48 * 512 + lane * 8;
    const short* ktf1 = KTF + (size_t)(hn * 2 + 1) * 48 * 512 + lane * 8;

#pragma unroll 4
    for (int kb = 0; kb < 48; kb += 2) {
        S8u a0[2], a1[2];
        short8 b0[2], b1[2];
#pragma unroll
        for (int q = 0; q < 2; ++q) {
            int kk = (kb + q) * 32;
            int dt = kk >> 7, c0 = (kk & 127) + quad * 8;
            int i0 = (hm * 32 + m + dt) * IN_S + c0;
            int i1 = i0 + 16 * IN_S;
            a0[q].h[0] = *(const short4_t*)&In[i0];
            a0[q].h[1] = *(const short4_t*)&In[i0 + 4];
            a1[q].h[0] = *(const short4_t*)&In[i1];
            a1[q].h[1] = *(const short4_t*)&In[i1 + 4];
            b0[q] = *(const short8*)(ktf0 + (kb + q) * 512);
            b1[q] = *(const short8*)(ktf1 + (kb + q) * 512);
        }
#pragma unroll
        for (int q = 0; q < 2; ++q) {
            acc[0][0] = __builtin_amdgcn_mfma_f32_16x16x32_bf16(a0[q].v, b0[q], acc[0][0], 0, 0, 0);
            acc[0][1] = __builtin_amdgcn_mfma_f32_16x16x32_bf16(a0[q].v, b1[q], acc[0][1], 0, 0, 0);
            acc[1][0] = __builtin_amdgcn_mfma_f32_16x16x32_bf16(a1[q].v, b0[q], acc[1][0], 0, 0, 0);
            acc[1][1] = __builtin_amdgcn_mfma_f32_16x16x32_bf16(a1[q].v, b1[q], acc[1][1], 0, 0, 0);
        }
    }

    float bias[2];
#pragma unroll
    for (int nt = 0; nt < 2; ++nt) {
        int u = hn * 32 + nt * 16 + m;
        bias[nt] = tb[u] + rb[u];
    }
#pragma unroll
    for (int mt = 0; mt < 2; ++mt)
#pragma unroll
        for (int r = 0; r < 4; ++r) {
            int t = hm * 32 + mt * 16 + quad * 4 + r;
            if (t >= 60) continue;
#pragma unroll
            for (int nt = 0; nt < 2; ++nt) {
                int u = hn * 32 + nt * 16 + m;
                float v = acc[mt][nt][r] + bias[nt];
                float sp = fmaxf(v, 0.f) + log1pf(__expf(-fabsf(v)));
                out[((size_t)(b * 60 + t) * 400 + n) * 64 + u] = sp;
            }
        }
}

// ---------------------------------------------------------------------------
extern "C" void kernel_launch(void* const* d_in, const int* in_sizes, int n_in,
                              void* d_out, int out_size, void* d_ws, size_t ws_size,
                              hipStream_t stream)
{
    const float* x    = (const float*)d_in[0];
    const float* A    = (const float*)d_in[1];
    const float* W1   = (const float*)d_in[2];
    const float* W2   = (const float*)d_in[3];
    const float* W3   = (const float*)d_in[4];
    const float* b1   = (const float*)d_in[5];
    const float* b2   = (const float*)d_in[6];
    const float* taW1 = (const float*)d_in[7];
    const float* taW2 = (const float*)d_in[8];
    const float* taW3 = (const float*)d_in[9];
    const float* Ve   = (const float*)d_in[10];
    const float* be   = (const float*)d_in[11];
    const float* tk   = (const float*)d_in[12];
    const float* tb   = (const float*)d_in[13];
    const float* rk   = (const float*)d_in[14];
    const float* rb   = (const float*)d_in[15];
    float* out = (float*)d_out;

    char* wsb = (char*)d_ws;
    size_t off = 0;
    auto alloc = [&](size_t bytes) -> void* {
        void* p = wsb + off;
        off += (bytes + 255) & ~(size_t)255;
        return p;
    };
    short* AWF           = (short*)alloc((size_t)186368 * 2);
    short* W2F           = (short*)alloc((size_t)25600 * 2);
    short* W3F           = (short*)alloc((size_t)4096 * 2);
    unsigned char* AbT   = (unsigned char*)alloc((size_t)400 * 448);
    short* xF            = (short*)alloc((size_t)480 * 26624 * 2);
    unsigned char* xF8   = (unsigned char*)alloc((size_t)480 * 26624);
    short* y             = (short*)alloc((size_t)480 * 400 * 64 * 2);
    float* r1            = (float*)alloc(480 * 64 * 4);
    float* rhs           = (float*)alloc(480 * 400 * 4);
    float* lhs           = (float*)alloc(480 * 400 * 4);
    float* Sbuf          = (float*)alloc(8 * 3600 * 4);
    float* ker           = (float*)alloc(8 * 3600 * 4);
    short* KTF           = (short*)alloc((size_t)98304 * 2);

    hipMemsetAsync(r1, 0, 480 * 64 * 4, stream);
    prep_w<<<806, 256, 0, stream>>>(A, W1, W2, W3, AWF, W2F, W3F, AbT);
    prep_xt<<<6240, 256, 0, stream>>>(x, xF, xF8);
    dgc_mfma<<<dim3(7, 480), 256, 0, stream>>>(b1, b2, (const unsigned*)AbT,
                                               AWF, W2F, W3F, xF, xF8,
                                               taW1, taW3, y, rhs, r1);
    ta_lhs<<<480, 256, 0, stream>>>(r1, taW2, lhs);
    ta_product<<<dim3(15, 8), 256, 0, stream>>>(lhs, rhs, be, Sbuf);
    ta_softmax<<<8, 256, 0, stream>>>(Sbuf, Ve, ker);
    ktf_prep<<<384, 256, 0, stream>>>(tk, rk, KTF);
    fused_conv<<<dim3(400, 8), 256, 0, stream>>>(y, ker, x, KTF, tb, rb, out);
}